// Round 5
// baseline (5729.542 us; speedup 1.0000x reference)
//
#include <hip/hip_runtime.h>
#include <stdint.h>

#define B_  16
#define T_  2048
#define D_  512

typedef short v8s __attribute__((ext_vector_type(8)));
typedef float v4f __attribute__((ext_vector_type(4)));

// ws layout (bytes)
#define WT_OFF   0u            // 8 MB  bf16 weight fragments
#define H0_OFF   8388608u      // 32 MB linear h0, bf16 packed [t][d/8][b][8], sentinel-filled
#define H1_OFF   41943040u     // 32 MB linear h1
#define XB_OFF   75497472u     // 32 MB x packed [t][d/8][b][8] bf16
#define WS_NEED  (XB_OFF + 33554432u)

#define SENT 0xFFFFFFFFu       // two bf16 NaNs; |h|<=1.0 -> valid words never match

__device__ __forceinline__ short f2bf(float f) {
  unsigned u = __builtin_bit_cast(unsigned, f);
  u = (u + 0x7FFFu + ((u >> 16) & 1u)) >> 16;
  return (short)u;
}
__device__ __forceinline__ float sigmoid_fast(float z) { return 1.f / (1.f + __expf(-z)); }
__device__ __forceinline__ float tanh_fast(float z) {
  float e = __expf(2.f * z);
  return 1.f - 2.f / (e + 1.f);
}
__device__ __forceinline__ unsigned long long cohLoadU2(const unsigned* p) {
  return __hip_atomic_load((unsigned long long*)p, __ATOMIC_RELAXED, __HIP_MEMORY_SCOPE_AGENT);
}
__device__ __forceinline__ void cohStoreU(unsigned* p, unsigned v) {
  __hip_atomic_store(p, v, __ATOMIC_RELAXED, __HIP_MEMORY_SCOPE_AGENT);
}

// Wx/Wh fp32 [L][512][2048] -> bf16 MFMA B-fragment order (unchanged, validated)
__global__ void prep_weights(const float* __restrict__ Wx, const float* __restrict__ Wh,
                             short* __restrict__ wT) {
  int tid = blockIdx.x * 256 + threadIdx.x;            // [0, 2^22)
  int l   = tid >> 21;
  int mat = (tid >> 20) & 1;
  int rem = tid & ((1 << 20) - 1);
  int k   = rem >> 11;
  int col = rem & 2047;
  const float* src = mat ? Wh : Wx;
  float v = src[(l << 20) + (k << 11) + col];
  int q = col >> 9, r9 = col & 511, g = r9 >> 3, jj = r9 & 7;
  int c = q * 8 + jj, ntile = c >> 4, n = c & 15;
  int kap = k >> 5, k5 = k & 31, quad = k5 >> 3, j = k5 & 7;
  int lane = quad * 16 + n;
  int dst = ((((l * 2 + mat) * 64 + g) * 2 + ntile) * 16 + kap) * 512 + lane * 8 + j;
  wT[dst] = f2bf(v);
}

// x [b][t][d] fp32 -> packed xP[t][d/8][b][d%8] bf16, AND sentinel-fill both h
// buffers (h0+h1 = 16M u32 words == grid size 2^24, contiguous at H0_OFF).
__global__ void prep_x(const float* __restrict__ x, short* __restrict__ xP,
                       unsigned* __restrict__ hwords) {
  int tid = blockIdx.x * 256 + threadIdx.x;            // [0, 2^24)
  hwords[tid] = SENT;
  int b = tid >> 20, r = tid & ((1 << 20) - 1), t = r >> 9, d = r & 511;
  xP[(size_t)t * 8192 + (d >> 3) * 128 + b * 8 + (d & 7)] = f2bf(x[tid]);
}

// 8 half-slice A-fragments via agent-scope (IF$) loads; returns running max.
// mx == SENT  <=>  at least one word still unwritten.
__device__ __forceinline__ unsigned coh_load8(const short* p, v8s afr[8]) {
  unsigned mx = 0;
#pragma unroll
  for (int kk = 0; kk < 8; ++kk) {
    const unsigned* q = (const unsigned*)(p + kk * 512);
    unsigned long long w0 = cohLoadU2(q);
    unsigned long long w1 = cohLoadU2(q + 2);
    unsigned a = (unsigned)w0, b = (unsigned)(w0 >> 32);
    unsigned c = (unsigned)w1, d = (unsigned)(w1 >> 32);
    mx = a > mx ? a : mx;
    mx = b > mx ? b : mx;
    mx = c > mx ? c : mx;
    mx = d > mx ? d : mx;
    uint4 pk; pk.x = a; pk.y = b; pk.z = c; pk.w = d;
    afr[kk] = __builtin_bit_cast(v8s, pk);
  }
  return mx;
}

// 32 MFMAs: 8 K-fragments x 4 n-tiles, 4 independent accumulator chains
__device__ __forceinline__ void mfma32(const v8s afr[8], const v8s wfr[4][8], v4f acc[4]) {
#pragma unroll
  for (int kk = 0; kk < 8; ++kk) {
#pragma unroll
    for (int nt = 0; nt < 4; ++nt)
      acc[nt] = __builtin_amdgcn_mfma_f32_16x16x32_bf16(afr[kk], wfr[nt][kk], acc[nt], 0, 0, 0);
  }
}

__global__ __launch_bounds__(256, 1) void lstm_persist(
    const float* __restrict__ x, const short* __restrict__ xP,
    const short* __restrict__ wT, const float* __restrict__ bias,
    short* h0, short* h1, float* __restrict__ out) {
  const int wg   = blockIdx.x;
  const int l    = wg >> 5;       // layer 0 or 1
  const int g    = wg & 31;       // column group (16 h-cols)
  const int tid  = threadIdx.x;
  const int wave = tid >> 6;
  const int lane = tid & 63;
  const int m    = wave >> 1;     // 0 = input kernel, 1 = recurrent
  const int kh   = wave & 1;      // K-half this wave covers: [kh*256, kh*256+256)
  const int n15  = lane & 15;
  const int quad = lane >> 4;

  // gate partials: [buf][wave][batch row][4 ntiles x 16 + pad12]
  // row stride 76 (== 12 mod 32 banks): epilogue float2 reads land 2-way (free)
  __shared__ float LDSG[2][4][16][76];

  short* hOwn = l ? h1 : h0;

  // loop-invariant B fragments -> VGPRs: 4 n-tiles x 8 K-frags (128 VGPR)
  v8s wfr[4][8];
#pragma unroll
  for (int nt = 0; nt < 4; ++nt) {
    const int gOld = 2 * g + (nt >> 1);
    const int nt2  = nt & 1;
    const short* wb = wT + (size_t)((((l * 2 + m) * 64 + gOld) * 2 + nt2) * 16 + kh * 8) * 512 + lane * 8;
#pragma unroll
    for (int kk = 0; kk < 8; ++kk) wfr[nt][kk] = *(const v8s*)(wb + kk * 512);
  }

  // epilogue state (waves 0,1): eIdx -> (batch bb, col-pair jp): cols g*16+2jp, +1
  const int eIdx = wave * 64 + lane;   // [0,128)
  const int bb = eIdx >> 3, jp = eIdx & 7;
  const int hi = jp >> 2;              // which old 8-col half
  const int jj = 2 * (jp & 3);         // even col within the 8
  float bq[4][2];
#pragma unroll
  for (int q = 0; q < 4; ++q) {
    bq[q][0] = bias[l * 2048 + q * 512 + g * 16 + 2 * jp];
    bq[q][1] = bias[l * 2048 + q * 512 + g * 16 + 2 * jp + 1];
  }
  float c0 = 0.f, c1 = 0.f;

  const int aOff = kh * 4096 + quad * 128 + n15 * 8;  // half-slice A offset (shorts)

  for (int t = 0; t < T_; ++t) {
    const int buf = t & 1;

    // residual x prefetch (waves 0,1 / l1): issue early, consume in epilogue
    float2 xv;
    size_t xi = 0;
    if (l == 1 && wave < 2) {
      xi = (size_t)bb * (T_ * D_) + (size_t)t * D_ + g * 16 + 2 * jp;
      xv = *(const float2*)(x + xi);
    }

    v4f acc[4];
#pragma unroll
    for (int nt = 0; nt < 4; ++nt) acc[nt] = (v4f){0.f, 0.f, 0.f, 0.f};

    const short* hp = nullptr;
    if (m == 0) {
      if (l == 0) {
        const short* p = xP + (size_t)t * 8192 + aOff;   // static input, plain loads
        v8s afr[8];
#pragma unroll
        for (int kk = 0; kk < 8; ++kk) afr[kk] = *(const v8s*)(p + kk * 512);
        mfma32(afr, wfr, acc);
      } else {
        hp = h0 + (size_t)t * 8192 + aOff;               // layer-0 output, step t
      }
    } else if (t > 0) {
      hp = hOwn + (size_t)(t - 1) * 8192 + aOff;         // own recurrence, step t-1
    }

    if (hp) {
      v8s afr[8];
      // Paced first probe for the own-recurrence stream: h(t-1) becomes
      // visible only ~1000cy after the barrier (epilogue + store->IF$);
      // an immediate probe is structurally doomed and costs a full RTT.
      if (m == 1) __builtin_amdgcn_s_sleep(12);
      unsigned mx = coh_load8(hp, afr);
      while (__ballot(mx == SENT) != 0) {                // validate BEFORE multiply
        __builtin_amdgcn_s_sleep(1);
        mx = coh_load8(hp, afr);
      }
      mfma32(afr, wfr, acc);
    }

#pragma unroll
    for (int nt = 0; nt < 4; ++nt) {
      const int rb = quad * 4;
#pragma unroll
      for (int r = 0; r < 4; ++r)
        LDSG[buf][wave][rb + r][nt * 16 + n15] = acc[nt][r];
    }
    __syncthreads();   // single barrier per step (LDSG double-buffered)

    // ---------- epilogue on waves 0+1: gates -> (c,h), fire-and-forget publish ----------
    if (wave < 2) {
      float2 s[4];
#pragma unroll
      for (int q = 0; q < 4; ++q) {
        const int coff = (hi * 2 + (q >> 1)) * 16 + (q & 1) * 8 + jj;
        float2 a0 = *(const float2*)&LDSG[buf][0][bb][coff];
        float2 a1 = *(const float2*)&LDSG[buf][1][bb][coff];
        float2 a2 = *(const float2*)&LDSG[buf][2][bb][coff];
        float2 a3 = *(const float2*)&LDSG[buf][3][bb][coff];
        s[q].x = a0.x + a1.x + a2.x + a3.x + bq[q][0];
        s[q].y = a0.y + a1.y + a2.y + a3.y + bq[q][1];
      }
      float i0 = sigmoid_fast(s[0].x), i1 = sigmoid_fast(s[0].y);
      float f0 = sigmoid_fast(s[1].x), f1 = sigmoid_fast(s[1].y);
      float g0 = tanh_fast(s[2].x),    g1 = tanh_fast(s[2].y);
      float o0 = sigmoid_fast(s[3].x), o1 = sigmoid_fast(s[3].y);
      c0 = f0 * c0 + i0 * g0;
      c1 = f1 * c1 + i1 * g1;
      float h0v = o0 * tanh_fast(c0);
      float h1v = o1 * tanh_fast(c1);
      unsigned pack = (unsigned)(unsigned short)f2bf(h0v) |
                      ((unsigned)(unsigned short)f2bf(h1v) << 16);
      // |h|<=1 so pack never equals SENT; single atomic u32 store IS the handoff.
      cohStoreU((unsigned*)hOwn + (size_t)t * 4096 + (2 * g + hi) * 64 + bb * 4 + (jp & 3), pack);
      if (l == 1) {
        float2 ov; ov.x = h0v + xv.x; ov.y = h1v + xv.y;
        *(float2*)(out + xi) = ov;
      }
    }
  }
}

extern "C" void kernel_launch(void* const* d_in, const int* in_sizes, int n_in,
                              void* d_out, int out_size, void* d_ws, size_t ws_size,
                              hipStream_t stream) {
  const float* x    = (const float*)d_in[0];
  const float* Wx   = (const float*)d_in[1];
  const float* Wh   = (const float*)d_in[2];
  const float* bias = (const float*)d_in[3];
  float* out = (float*)d_out;

  char* ws   = (char*)d_ws;
  short* wT  = (short*)(ws + WT_OFF);
  short* h0  = (short*)(ws + H0_OFF);
  short* h1  = (short*)(ws + H1_OFF);
  short* xP  = (short*)(ws + XB_OFF);
  unsigned* hwords = (unsigned*)(ws + H0_OFF);   // h0+h1 contiguous, 2^24 words

  hipLaunchKernelGGL(prep_weights, dim3(16384), dim3(256), 0, stream, Wx, Wh, wT);
  hipLaunchKernelGGL(prep_x, dim3(65536), dim3(256), 0, stream, x, xP, hwords);
  hipLaunchKernelGGL(lstm_persist, dim3(64), dim3(256), 0, stream,
                     x, xP, wT, bias, h0, h1, out);
}